// Round 2
// baseline (3019.215 us; speedup 1.0000x reference)
//
#include <hip/hip_runtime.h>
#include <stdint.h>

#define DET_THRESH 0.015f

// =====================================================================
// Fused conv0(1->64,3x3)+relu -> conv1(64->64,3x3)+relu -> 2x2 maxpool
// in : (8,1,240,320)   out: (8,64,120,160)
// Tile 16x16 px, 16 co / block. 256 thr: c4(0..3) x lane(qy 0..15, xg 0..3).
// Each thread: 1 row x 4 cols x 4 co.
// =====================================================================
__global__ __launch_bounds__(256, 4) void k_fused01(
    const float* __restrict__ x, const float* __restrict__ w0g, const float* __restrict__ b0g,
    const float* __restrict__ w1g, const float* __restrict__ b1g, float* __restrict__ out)
{
  const int H = 240, W = 320;
  __shared__ float in_raw[20][20];
  __shared__ float a0[16][18][20];
  __shared__ float wt[2304];      // [ci][tap][co16]
  __shared__ float w0l[576];      // [ci64][tap9]
  __shared__ float b0l[64];

  int tile = blockIdx.x;              // 20 x 15 tiles
  int tx = tile % 20, ty = tile / 20;
  int x0 = tx * 16, y0 = ty * 16;
  int cb = blockIdx.y;                // 0..3
  int n  = blockIdx.z;

  int tid = threadIdx.x;
  int c4 = tid >> 6;
  int p  = tid & 63;
  int qy = p >> 2, xg = p & 3;
  int ox = xg << 2;

  // preload conv0 weights/bias + input tile (halo 2)
  for (int k = tid; k < 576; k += 256) w0l[k] = w0g[k];
  if (tid < 64) b0l[tid] = b0g[tid];
  for (int u = tid; u < 100; u += 256) {
    int row = u / 5, g = u % 5;
    int gy = y0 - 2 + row, gxb = x0 - 2 + 4 * g;
    float4 vv;
    float* vp = (float*)&vv;
#pragma unroll
    for (int v = 0; v < 4; v++) {
      int gx = gxb + v;
      vp[v] = (gy >= 0 && gy < H && gx >= 0 && gx < W) ? x[(size_t)n * H * W + gy * W + gx] : 0.f;
    }
    *(float4*)&in_raw[row][4 * g] = vv;
  }

  float acc[4][4];
#pragma unroll
  for (int j = 0; j < 4; j++)
#pragma unroll
    for (int v = 0; v < 4; v++) acc[j][v] = 0.f;

  for (int cc = 0; cc < 4; ++cc) {
    __syncthreads();   // prev conv1 done with a0/wt
    // stage conv1 weights for this ci-chunk
    for (int k = tid; k < 2304; k += 256) {
      int co = k / 144, r = k % 144;
      int ci = r / 9, tap = r % 9;
      wt[ci * 144 + tap * 16 + co] = w1g[((cb * 16 + co) * 64 + (cc * 16 + ci)) * 9 + tap];
    }
    // conv0 chunk -> a0 (force 0 outside image: conv1 'SAME' zero pad)
    for (int u = tid; u < 1440; u += 256) {
      int ci = u / 90, r = u % 90;
      int ry = r / 5, g = r % 5;
      int c0 = 4 * g;
      float rowv[3][6];
#pragma unroll
      for (int dy = 0; dy < 3; dy++) {
        float4 a4 = *(const float4*)&in_raw[ry + dy][c0];
        rowv[dy][0] = a4.x; rowv[dy][1] = a4.y; rowv[dy][2] = a4.z; rowv[dy][3] = a4.w;
      }
      if (g < 4) {
#pragma unroll
        for (int dy = 0; dy < 3; dy++) {
          float2 a2 = *(const float2*)&in_raw[ry + dy][c0 + 4];
          rowv[dy][4] = a2.x; rowv[dy][5] = a2.y;
        }
      }
      const float* wp = &w0l[(cc * 16 + ci) * 9];
      float bb = b0l[cc * 16 + ci];
      int gy = y0 - 1 + ry;
      int nv = (g < 4) ? 4 : 2;
      float ov[4];
#pragma unroll 4
      for (int v = 0; v < nv; v++) {
        int gx = x0 - 1 + c0 + v;
        float s = bb;
#pragma unroll
        for (int dy = 0; dy < 3; dy++)
#pragma unroll
          for (int dx = 0; dx < 3; dx++)
            s = fmaf(rowv[dy][v + dx], wp[dy * 3 + dx], s);
        ov[v] = (gy >= 0 && gy < H && gx >= 0 && gx < W) ? fmaxf(s, 0.f) : 0.f;
      }
      if (g < 4) {
        *(float4*)&a0[ci][ry][c0] = *(float4*)ov;
      } else {
        *(float2*)&a0[ci][ry][c0] = *(float2*)ov;
      }
    }
    __syncthreads();
    // conv1 main loop
    for (int ci = 0; ci < 16; ++ci) {
      float win[3][6];
#pragma unroll
      for (int r = 0; r < 3; r++) {
        float4 a4 = *(const float4*)&a0[ci][qy + r][ox];
        float2 a2 = *(const float2*)&a0[ci][qy + r][ox + 4];
        win[r][0] = a4.x; win[r][1] = a4.y; win[r][2] = a4.z; win[r][3] = a4.w;
        win[r][4] = a2.x; win[r][5] = a2.y;
      }
#pragma unroll
      for (int t = 0; t < 9; t++) {
        float4 wv = *(const float4*)&wt[ci * 144 + t * 16 + (c4 << 2)];
        int r = t / 3, cx = t % 3;
#pragma unroll
        for (int v = 0; v < 4; v++) {
          float a = win[r][cx + v];
          acc[0][v] = fmaf(a, wv.x, acc[0][v]);
          acc[1][v] = fmaf(a, wv.y, acc[1][v]);
          acc[2][v] = fmaf(a, wv.z, acc[2][v]);
          acc[3][v] = fmaf(a, wv.w, acc[3][v]);
        }
      }
    }
  }

  // bias + relu + 2x2 maxpool (row pair via shfl_xor lane^4) + store
  int Hp = 120, Wp = 160;
  int py = (y0 + qy) >> 1;
  int px = (x0 + ox) >> 1;
#pragma unroll
  for (int j = 0; j < 4; j++) {
    int co = cb * 16 + (c4 << 2) + j;
    float bb = b1g[co];
    float v0 = fmaxf(acc[j][0] + bb, 0.f);
    float v1 = fmaxf(acc[j][1] + bb, 0.f);
    float v2 = fmaxf(acc[j][2] + bb, 0.f);
    float v3 = fmaxf(acc[j][3] + bb, 0.f);
    float h0 = fmaxf(v0, v1), h1 = fmaxf(v2, v3);
    float g0 = fmaxf(h0, __shfl_xor(h0, 4, 64));
    float g1 = fmaxf(h1, __shfl_xor(h1, 4, 64));
    if ((qy & 1) == 0) {
      float2 o2 = make_float2(g0, g1);
      *(float2*)&out[(((size_t)n * 64 + co) * Hp + py) * Wp + px] = o2;
    }
  }
}

// =====================================================================
// Generic 3x3 conv (+bias+relu), optional fused 2x2 maxpool epilogue.
// CIN, COUT multiples of 16. Tile 16x16, thread = 1 row x 4 cols x 4 co.
// =====================================================================
template <bool POOL>
__global__ __launch_bounds__(256, 4) void k_conv(
    const float* __restrict__ in, const float* __restrict__ wg, const float* __restrict__ bg,
    float* __restrict__ out, int CIN, int COUT, int H, int W, int tilesX)
{
  __shared__ float ain[16][18][20];
  __shared__ float wt[2304];

  int tile = blockIdx.x;
  int tx = tile % tilesX, ty = tile / tilesX;
  int x0 = tx * 16, y0 = ty * 16;
  int cb = blockIdx.y;
  int n  = blockIdx.z;

  int tid = threadIdx.x;
  int c4 = tid >> 6;
  int p  = tid & 63;
  int qy = p >> 2, xg = p & 3;
  int ox = xg << 2;

  float acc[4][4];
#pragma unroll
  for (int j = 0; j < 4; j++)
#pragma unroll
    for (int v = 0; v < 4; v++) acc[j][v] = 0.f;

  int nchunks = CIN >> 4;
  for (int cc = 0; cc < nchunks; ++cc) {
    __syncthreads();
    // stage activations (16ci x 18 x 18, padded stride 20)
    for (int u = tid; u < 1440; u += 256) {
      int ci = u / 90, r = u % 90;
      int ry = r / 5, g = r % 5;
      int c0 = 4 * g;
      int gy = y0 - 1 + ry;
      const float* src = in + (((size_t)n * CIN + cc * 16 + ci) * H + gy) * W;
      int nv = (g < 4) ? 4 : 2;
      float ov[4];
#pragma unroll 4
      for (int v = 0; v < nv; v++) {
        int gx = x0 - 1 + c0 + v;
        ov[v] = (gy >= 0 && gy < H && gx >= 0 && gx < W) ? src[gx] : 0.f;
      }
      if (g < 4) *(float4*)&ain[ci][ry][c0] = *(float4*)ov;
      else       *(float2*)&ain[ci][ry][c0] = *(float2*)ov;
    }
    // stage weights
    for (int k = tid; k < 2304; k += 256) {
      int co = k / 144, r = k % 144;
      int ci = r / 9, tap = r % 9;
      wt[ci * 144 + tap * 16 + co] = wg[((size_t)(cb * 16 + co) * CIN + (cc * 16 + ci)) * 9 + tap];
    }
    __syncthreads();
    for (int ci = 0; ci < 16; ++ci) {
      float win[3][6];
#pragma unroll
      for (int r = 0; r < 3; r++) {
        float4 a4 = *(const float4*)&ain[ci][qy + r][ox];
        float2 a2 = *(const float2*)&ain[ci][qy + r][ox + 4];
        win[r][0] = a4.x; win[r][1] = a4.y; win[r][2] = a4.z; win[r][3] = a4.w;
        win[r][4] = a2.x; win[r][5] = a2.y;
      }
#pragma unroll
      for (int t = 0; t < 9; t++) {
        float4 wv = *(const float4*)&wt[ci * 144 + t * 16 + (c4 << 2)];
        int r = t / 3, cx = t % 3;
#pragma unroll
        for (int v = 0; v < 4; v++) {
          float a = win[r][cx + v];
          acc[0][v] = fmaf(a, wv.x, acc[0][v]);
          acc[1][v] = fmaf(a, wv.y, acc[1][v]);
          acc[2][v] = fmaf(a, wv.z, acc[2][v]);
          acc[3][v] = fmaf(a, wv.w, acc[3][v]);
        }
      }
    }
  }

  if (POOL) {
    int Hp = H >> 1, Wp = W >> 1;
    int py = (y0 + qy) >> 1;
    int px = (x0 + ox) >> 1;
    bool ok = ((qy & 1) == 0) && (py < Hp) && (px + 1 < Wp);
#pragma unroll
    for (int j = 0; j < 4; j++) {
      int co = cb * 16 + (c4 << 2) + j;
      float bb = bg[co];
      float v0 = fmaxf(acc[j][0] + bb, 0.f);
      float v1 = fmaxf(acc[j][1] + bb, 0.f);
      float v2 = fmaxf(acc[j][2] + bb, 0.f);
      float v3 = fmaxf(acc[j][3] + bb, 0.f);
      float h0 = fmaxf(v0, v1), h1 = fmaxf(v2, v3);
      float g0 = fmaxf(h0, __shfl_xor(h0, 4, 64));
      float g1 = fmaxf(h1, __shfl_xor(h1, 4, 64));
      if (ok) {
        float2 o2 = make_float2(g0, g1);
        *(float2*)&out[(((size_t)n * COUT + co) * Hp + py) * Wp + px] = o2;
      }
    }
  } else {
    int y = y0 + qy;
    if (y < H) {
      int xb = x0 + ox;
      bool full = (xb + 3) < W;
#pragma unroll
      for (int j = 0; j < 4; j++) {
        int co = cb * 16 + (c4 << 2) + j;
        float bb = bg[co];
        float ov[4];
#pragma unroll
        for (int v = 0; v < 4; v++) ov[v] = fmaxf(acc[j][v] + bb, 0.f);
        float* dst = out + (((size_t)n * COUT + co) * H + y) * W + xb;
        if (full) {
          *(float4*)dst = *(float4*)ov;
        } else {
#pragma unroll
          for (int v = 0; v < 4; v++)
            if (xb + v < W) dst[v] = ov[v];
        }
      }
    }
  }
}

// =====================================================================
// Head: conv9 (1x1, 256->65) + bias + softmax(65) + drop dustbin + pixel shuffle
// =====================================================================
__global__ __launch_bounds__(256) void k_head(
    const float* __restrict__ act, const float* __restrict__ w9, const float* __restrict__ b9,
    float* __restrict__ prob)
{
  __shared__ float wl[256 * 68];   // [ci][co pad 68]
  int n = blockIdx.y;
  int tid = threadIdx.x;
  for (int k = tid; k < 65 * 256; k += 256) {
    int co = k / 256, ci = k % 256;
    wl[ci * 68 + co] = w9[k];
  }
  for (int ci = tid; ci < 256; ci += 256) {
    wl[ci * 68 + 65] = 0.f; wl[ci * 68 + 66] = 0.f; wl[ci * 68 + 67] = 0.f;
  }
  __syncthreads();
  int px = blockIdx.x * 256 + tid;
  if (px >= 1200) return;

  float accv[68];
#pragma unroll
  for (int i = 0; i < 68; i++) accv[i] = 0.f;

  for (int ci = 0; ci < 256; ++ci) {
    float a = act[((size_t)n * 256 + ci) * 1200 + px];
    const float4* wp = (const float4*)&wl[ci * 68];
#pragma unroll
    for (int g = 0; g < 17; g++) {
      float4 wv = wp[g];
      accv[g * 4 + 0] = fmaf(a, wv.x, accv[g * 4 + 0]);
      accv[g * 4 + 1] = fmaf(a, wv.y, accv[g * 4 + 1]);
      accv[g * 4 + 2] = fmaf(a, wv.z, accv[g * 4 + 2]);
      accv[g * 4 + 3] = fmaf(a, wv.w, accv[g * 4 + 3]);
    }
  }
#pragma unroll
  for (int co = 0; co < 65; co++) accv[co] += b9[co];
  float m = accv[0];
#pragma unroll
  for (int co = 1; co < 65; co++) m = fmaxf(m, accv[co]);
  float s = 0.f;
#pragma unroll
  for (int co = 0; co < 65; co++) { accv[co] = __expf(accv[co] - m); s += accv[co]; }
  float inv = 1.f / s;

  int hc = px / 40, wc = px % 40;
  float* pb = prob + (size_t)n * 76800;
#pragma unroll
  for (int co = 0; co < 64; co++) {
    pb[(hc * 8 + (co >> 3)) * 320 + wc * 8 + (co & 7)] = accv[co] * inv;
  }
}

// =====================================================================
// Exact reference NMS per image.
// =====================================================================
#define MAXC 1024
__global__ __launch_bounds__(1024) void k_nms(
    const float* __restrict__ prob, float* __restrict__ onms, float* __restrict__ opred)
{
  __shared__ unsigned sup[MAXC * 32];
  __shared__ unsigned long long skey[MAXC];
  __shared__ unsigned syx[MAXC];
  __shared__ unsigned hist[256];
  __shared__ unsigned vword[32];
  __shared__ unsigned sh_prefix, sh_K, sh_cG, sh_pG, sh_pE;

  int n = blockIdx.x;
  int tid = threadIdx.x;
  const float* p = prob + (size_t)n * 76800;
  float* on = onms + (size_t)n * 76800;
  float* op = opred + (size_t)n * 76800;

  for (int k = tid; k < 76800; k += 1024) { on[k] = 0.f; op[k] = 0.f; }

  if (tid == 0) { sh_prefix = 0u; sh_K = MAXC; sh_cG = 0u; sh_pG = 0u; sh_pE = 0u; }

  for (int round = 0; round < 4; ++round) {
    if (tid < 256) hist[tid] = 0u;
    __syncthreads();
    unsigned prefix = sh_prefix;
    int shift = 24 - 8 * round;
    unsigned maskHi = (round == 0) ? 0u : (0xFFFFFFFFu << (shift + 8));
    for (int k = tid; k < 76800; k += 1024) {
      unsigned b = __float_as_uint(p[k]);
      if ((b & maskHi) == prefix) atomicAdd(&hist[(b >> shift) & 255], 1u);
    }
    __syncthreads();
    if (tid == 0) {
      unsigned K = sh_K, cum = 0u;
      int bin = 255;
      for (; bin >= 0; --bin) {
        unsigned c = hist[bin];
        if (cum + c >= K) break;
        cum += c;
      }
      sh_prefix = prefix | ((unsigned)bin << shift);
      sh_K = K - cum;
      sh_cG += cum;
    }
    __syncthreads();
  }
  unsigned T = sh_prefix;
  unsigned Kfill = sh_K;
  unsigned Cgt = sh_cG;

  unsigned* eq = sup;
  __syncthreads();
  for (int k = tid; k < 76800; k += 1024) {
    unsigned b = __float_as_uint(p[k]);
    if (b > T) {
      unsigned pos = atomicAdd(&sh_pG, 1u);
      skey[pos] = ((unsigned long long)b << 32) | (unsigned)(~(unsigned)k);
    } else if (b == T) {
      unsigned pos = atomicAdd(&sh_pE, 1u);
      if (pos < 2048u) eq[pos] = (unsigned)k;
    }
  }
  __syncthreads();
  unsigned cE = sh_pE;
  for (int k = tid; k < 2048; k += 1024)
    if ((unsigned)k >= cE) eq[k] = 0xFFFFFFFFu;
  __syncthreads();
  for (int k = 2; k <= 2048; k <<= 1) {
    for (int j = k >> 1; j > 0; j >>= 1) {
      int t = tid;
      int i = ((t & ~(j - 1)) << 1) | (t & (j - 1));
      int l = i | j;
      bool up = ((i & k) == 0);
      unsigned a = eq[i], b2 = eq[l];
      if (up ? (a > b2) : (a < b2)) { eq[i] = b2; eq[l] = a; }
      __syncthreads();
    }
  }
  for (int m2 = tid; m2 < (int)Kfill; m2 += 1024)
    skey[Cgt + m2] = ((unsigned long long)T << 32) | (unsigned)(~eq[m2]);
  __syncthreads();

  for (int k = 2; k <= MAXC; k <<= 1) {
    for (int j = k >> 1; j > 0; j >>= 1) {
      int i = tid;
      int l = i ^ j;
      if (l > i) {
        unsigned long long a = skey[i], b2 = skey[l];
        bool up = ((i & k) == 0);
        if (up ? (a < b2) : (a > b2)) { skey[i] = b2; skey[l] = a; }
      }
      __syncthreads();
    }
  }

  if (tid < 32) vword[tid] = 0u;
  __syncthreads();
  {
    unsigned long long key = skey[tid];
    unsigned vb = (unsigned)(key >> 32);
    float val = __uint_as_float(vb);
    unsigned id = ~(unsigned)key;
    unsigned y = id / 320u, x = id - 320u * y;
    syx[tid] = (y << 16) | x;
    if (val > DET_THRESH) atomicOr(&vword[tid >> 5], 1u << (tid & 31));
  }
  __syncthreads();

  {
    unsigned myyx = syx[tid];
    int ty = (int)(myyx >> 16), tx = (int)(myyx & 0xFFFFu);
    for (int w = 0; w < 32; ++w) {
      unsigned bits = 0u;
#pragma unroll 8
      for (int b2 = 0; b2 < 32; ++b2) {
        int j = w * 32 + b2;
        if (j > tid) {
          unsigned o = syx[j];
          int dy = ty - (int)(o >> 16); dy = dy < 0 ? -dy : dy;
          int dx = tx - (int)(o & 0xFFFFu); dx = dx < 0 ? -dx : dx;
          if (((dy | dx) < 4) && (dy + dx) <= 4) bits |= 1u << b2;
        }
      }
      sup[tid * 32 + w] = bits;
    }
  }
  __syncthreads();

  if (tid < 64) {
    int lw = tid;
    unsigned keepw = (lw < 32) ? vword[lw] : 0u;
    for (int i = 0; i < MAXC; ++i) {
      unsigned kword = __shfl(keepw, i >> 5, 64);
      if ((kword >> (i & 31)) & 1u) {
        if (lw < 32) keepw &= ~sup[i * 32 + lw];
      }
    }
    unsigned pc = (lw < 32) ? (unsigned)__builtin_popcount(keepw) : 0u;
    unsigned incl = pc;
    for (int d = 1; d < 32; d <<= 1) {
      unsigned t2 = __shfl_up(incl, d, 64);
      if (lw >= d) incl += t2;
    }
    unsigned excl = incl - pc;
    if (lw < 32) {
      int quota = 300 - (int)excl;
      if (quota <= 0) keepw = 0u;
      else if ((int)pc > quota) {
        while (__builtin_popcount(keepw) > quota)
          keepw &= ~(1u << (31 - __builtin_clz(keepw)));
      }
      unsigned kw = keepw;
      while (kw) {
        int b2 = __builtin_ffs((int)kw) - 1;
        kw &= kw - 1u;
        int i = lw * 32 + b2;
        unsigned long long key = skey[i];
        float v = __uint_as_float((unsigned)(key >> 32));
        unsigned id = ~(unsigned)key;
        on[id] = v;
        op[id] = v;
      }
    }
  }
}

// =====================================================================
extern "C" void kernel_launch(void* const* d_in, const int* in_sizes, int n_in,
                              void* d_out, int out_size, void* d_ws, size_t ws_size,
                              hipStream_t stream) {
  const float* x = (const float*)d_in[0];
  const float* w[10];
  const float* b[10];
  for (int i = 0; i < 10; ++i) {
    w[i] = (const float*)d_in[1 + 2 * i];
    b[i] = (const float*)d_in[2 + 2 * i];
  }
  float* A = (float*)d_ws;
  float* B = A + 9830400;       // 64*120*160*8
  float* prob  = (float*)d_out;
  float* onms  = prob + 614400; // 8*240*320
  float* opred = onms + 614400;

  k_fused01<<<dim3(300, 4, 8), 256, 0, stream>>>(x, w[0], b[0], w[1], b[1], A);
  k_conv<false><<<dim3(80, 4, 8), 256, 0, stream>>>(A, w[2], b[2], B, 64, 64, 120, 160, 10);
  k_conv<true ><<<dim3(80, 4, 8), 256, 0, stream>>>(B, w[3], b[3], A, 64, 64, 120, 160, 10);
  k_conv<false><<<dim3(20, 8, 8), 256, 0, stream>>>(A, w[4], b[4], B, 64, 128, 60, 80, 5);
  k_conv<true ><<<dim3(20, 8, 8), 256, 0, stream>>>(B, w[5], b[5], A, 128, 128, 60, 80, 5);
  k_conv<false><<<dim3(6, 8, 8), 256, 0, stream>>>(A, w[6], b[6], B, 128, 128, 30, 40, 3);
  k_conv<false><<<dim3(6, 8, 8), 256, 0, stream>>>(B, w[7], b[7], A, 128, 128, 30, 40, 3);
  k_conv<false><<<dim3(6, 16, 8), 256, 0, stream>>>(A, w[8], b[8], B, 128, 256, 30, 40, 3);
  k_head<<<dim3(5, 8), 256, 0, stream>>>(B, w[9], b[9], prob);
  k_nms<<<dim3(8), 1024, 0, stream>>>(prob, onms, opred);
}